// Round 10
// baseline (5521.518 us; speedup 1.0000x reference)
//
#include <hip/hip_runtime.h>
#include <math.h>

#define TQ 256
#define DQ 512
#define GQ 2048

typedef __attribute__((ext_vector_type(8))) short bf16x8;
typedef __attribute__((ext_vector_type(4))) float f32x4;
typedef __attribute__((ext_vector_type(4))) unsigned u32x4;

__device__ __forceinline__ unsigned f2bf(float x) {
    unsigned u = __builtin_bit_cast(unsigned, x);
    return (u + 0x7fffu + ((u >> 16) & 1u)) >> 16;
}
__device__ __forceinline__ float bf2f(unsigned s) {
    return __builtin_bit_cast(float, s << 16);
}
__device__ __forceinline__ float sigf(float x) { return 1.f / (1.f + __expf(-x)); }
__device__ __forceinline__ float tanhfast(float x) { return 1.f - 2.f / (__expf(2.f * x) + 1.f); }

// L1-bypass 16B load (frames are write-once per layer; L2 fills are fresh)
__device__ __forceinline__ bf16x8 frag_load16(const unsigned short* p) {
    bf16x8 r;
    asm volatile("global_load_dwordx4 %0, %1, off sc0" : "=v"(r) : "v"(p));
    return r;
}

// ---------------- embedding + predicate concat -> xRaw[t][d][b] --------------
__global__ __launch_bounds__(256) void k_embed(const int* __restrict__ wid,
                                               const int* __restrict__ pid,
                                               const float* __restrict__ emb,
                                               float* __restrict__ xT) {
    __shared__ float Ls[64][65];
    int t = blockIdx.x;
    int d0 = blockIdx.y * 64;
    int tid = threadIdx.x;
    int l = tid & 63;
    int grp = tid >> 6;
#pragma unroll 4
    for (int bb = 0; bb < 16; ++bb) {
        int b = grp * 16 + bb;
        int d = d0 + l;
        float v;
        if (d < 511) v = emb[(size_t)wid[b * TQ + t] * 511 + d];
        else         v = (float)pid[b * TQ + t];
        Ls[l][b] = v;
    }
    __syncthreads();
#pragma unroll 4
    for (int dd = 0; dd < 16; ++dd) {
        int dl = grp * 16 + dd;
        xT[((size_t)t * DQ + d0 + dl) * 64 + l] = Ls[dl][l];
    }
}

// ---------------- xRaw -> x fragments (layer-0 input) ------------------------
__global__ __launch_bounds__(256) void k_convX(const float* __restrict__ xT,
                                               unsigned short* __restrict__ Xh,
                                               unsigned short* __restrict__ Xl) {
    int idx = blockIdx.x * 256 + threadIdx.x;    // (t*512 + d)*64 + b
    int b = idx & 63;
    int d = (idx >> 6) & 511;
    int t = idx >> 15;
    float v = xT[idx];
    unsigned hi = f2bf(v);
    unsigned lo = f2bf(v - bf2f(hi));
    size_t wi = (((size_t)(1 + t) * 4 + (b >> 4)) * 16 + (d >> 5)) * 512 +
                (((d >> 3) & 3) * 16 + (b & 15)) * 8 + (d & 7);
    Xh[wi] = (unsigned short)hi;
    Xl[wi] = (unsigned short)lo;
}

// ---------------- W -> A-operand fragments (m = col) -------------------------
__global__ __launch_bounds__(256) void k_convW(const float* __restrict__ Ws,
                                               unsigned short* __restrict__ Wh,
                                               unsigned short* __restrict__ Wl) {
    int idx = blockIdx.x * 256 + threadIdx.x;    // (lay*512 + d)*2048 + c
    int c = idx & 2047;
    int d = (idx >> 11) & 511;
    int lay = idx >> 20;
    float v = Ws[idx];
    unsigned hi = f2bf(v);
    unsigned lo = f2bf(v - bf2f(hi));
    size_t wi = (((size_t)lay * 128 + (c >> 4)) * 16 + (d >> 5)) * 512 +
                (((d >> 3) & 3) * 16 + (c & 15)) * 8 + (d & 7);
    Wh[wi] = (unsigned short)hi;
    Wl[wi] = (unsigned short)lo;
}

// ---------------- U -> B-operand fragments (n = (g&1)*8 + jl) ----------------
__global__ __launch_bounds__(256) void k_convU(const float* __restrict__ Us,
                                               unsigned short* __restrict__ Uh,
                                               unsigned short* __restrict__ Ul) {
    int idx = blockIdx.x * 256 + threadIdx.x;    // (lay*512 + k)*2048 + c
    int c = idx & 2047;
    int k = (idx >> 11) & 511;
    int lay = idx >> 20;
    float v = Us[idx];
    unsigned hi = f2bf(v);
    unsigned lo = f2bf(v - bf2f(hi));
    int g = c >> 9;
    int o = (c >> 3) & 63;
    int jl = c & 7;
    int nt = g >> 1;
    int n = (g & 1) * 8 + jl;
    size_t wi = ((((size_t)lay * 64 + o) * 16 + (k >> 5)) * 2 + nt) * 512 +
                (((k >> 3) & 3) * 16 + n) * 8 + (k & 7);
    Uh[wi] = (unsigned short)hi;
    Ul[wi] = (unsigned short)lo;
}

// ---------------- fused layer kernel ----------------
// grid = 256 WGs x 512 thr. WG < 128: recurrence (o = wg>>1 owns 8 units,
// half = wg&1 owns 32 batch). WG >= 128: pre-producer (x@W tiles + per-sl flag).
__global__ __launch_bounds__(512, 1) void k_fused(
    const unsigned short* __restrict__ Uh, const unsigned short* __restrict__ Ul,
    const unsigned short* __restrict__ Wh, const unsigned short* __restrict__ Wl,
    const unsigned short* __restrict__ Xih, const unsigned short* __restrict__ Xil,
    unsigned short* __restrict__ Xoh, unsigned short* __restrict__ Xol,
    float* __restrict__ preF, const int* __restrict__ mask,
    const float* __restrict__ bias, float* __restrict__ xT32,
    unsigned* __restrict__ bar, int flip, int writeX)
{
    __shared__ char ldsraw[81920];     // force 1 WG/CU; union of roles
    int wg = blockIdx.x;
    int tid = threadIdx.x;
    int w = tid >> 6, l = tid & 63;
    unsigned* pre_cnt = bar + 1024;

    if (wg >= 128) {
        // ================= pre-producer role =================
        float* stage = (float*)ldsraw + w * (16 * 68);
        int q = wg - 128;
        for (int T = q; T < 4096; T += 128) {
            int sl = T >> 4, cg = T & 15;
            int t_in = flip ? (255 - sl) : sl;
            int ct = cg * 8 + w;
            size_t xb = (size_t)(1 + t_in) * 32768 + (size_t)l * 8;
            f32x4 acc[4];
            f32x4 zv = {0.f, 0.f, 0.f, 0.f};
#pragma unroll
            for (int bt = 0; bt < 4; ++bt) acc[bt] = zv;

#pragma unroll 2
            for (int kt = 0; kt < 16; ++kt) {
                size_t wa = ((size_t)ct * 16 + kt) * 512 + l * 8;
                bf16x8 ah = *(const bf16x8*)(Wh + wa);
                bf16x8 al = *(const bf16x8*)(Wl + wa);
                bf16x8 bh[4], bo[4];
#pragma unroll
                for (int bt = 0; bt < 4; ++bt) {
                    size_t a = xb + (size_t)(bt * 16 + kt) * 512;
                    bh[bt] = *(const bf16x8*)(Xih + a);
                    bo[bt] = *(const bf16x8*)(Xil + a);
                }
#pragma unroll
                for (int bt = 0; bt < 4; ++bt) {
                    acc[bt] = __builtin_amdgcn_mfma_f32_16x16x32_bf16(ah, bh[bt], acc[bt], 0, 0, 0);
                    acc[bt] = __builtin_amdgcn_mfma_f32_16x16x32_bf16(al, bh[bt], acc[bt], 0, 0, 0);
                    acc[bt] = __builtin_amdgcn_mfma_f32_16x16x32_bf16(ah, bo[bt], acc[bt], 0, 0, 0);
                }
            }
            // stage (wave-local) then 16B coherent stores
#pragma unroll
            for (int bt = 0; bt < 4; ++bt)
#pragma unroll
                for (int r = 0; r < 4; ++r)
                    stage[((l >> 4) * 4 + r) * 68 + bt * 16 + (l & 15)] = acc[bt][r];
#pragma unroll
            for (int p = 0; p < 4; ++p) {
                int cr = p * 4 + (l >> 4);
                float bv = bias[ct * 16 + cr];
                f32x4 v = *(f32x4*)&stage[cr * 68 + (l & 15) * 4];
                v[0] += bv; v[1] += bv; v[2] += bv; v[3] += bv;
                float* dst = &preF[((size_t)sl * GQ + ct * 16 + cr) * 64 + (l & 15) * 4];
                asm volatile("global_store_dwordx4 %0, %1, off sc0 sc1" :: "v"(dst), "v"(v));
            }
            __syncthreads();   // drains vmcnt for all waves
            if (tid == 0)
                __hip_atomic_fetch_add(&pre_cnt[sl], 1u, __ATOMIC_RELAXED,
                                       __HIP_MEMORY_SCOPE_AGENT);
        }
        return;
    }

    // ================= recurrence role =================
    int o = wg >> 1, half = wg & 1;
    int kh = w >> 1, mq = w & 1;
    int mt = half * 2 + mq;            // global 16-batch tile
    float* part = (float*)ldsraw;      // [128][33]
    unsigned* hlds = (unsigned*)(ldsraw + 16896);  // [8][32]

    // resident U fragments (hi + lo) for this wave's k-quarter
    bf16x8 BH[4][2], BL[4][2];
#pragma unroll
    for (int kt2 = 0; kt2 < 4; ++kt2)
#pragma unroll
        for (int nt = 0; nt < 2; ++nt) {
            size_t a = (((size_t)o * 16 + kh * 4 + kt2) * 2 + nt) * 512 + l * 8;
            BH[kt2][nt] = *(const bf16x8*)(Uh + a);
            BL[kt2][nt] = *(const bf16x8*)(Ul + a);
        }

    int u8 = (tid >> 5) & 7;
    int bl = tid & 31;
    int jglob = o * 8 + u8;
    int bglob = half * 32 + bl;
    bool fin = tid < 256;

    float creg = 0.f, hpre = 0.f;
    float pzv[4];
    int maskv = 0;

    // prologue: wait for pre of sl=0, then prefetch finish operands
    if (tid == 0) {
        while (__hip_atomic_load(&pre_cnt[0], __ATOMIC_RELAXED,
                                 __HIP_MEMORY_SCOPE_AGENT) < 16u)
            __builtin_amdgcn_s_sleep(1);
    }
    __syncthreads();
    if (fin) {
        int t0 = flip ? 255 : 0;
        maskv = mask[bglob * TQ + t0];
#pragma unroll
        for (int g = 0; g < 4; ++g)
            pzv[g] = preF[(size_t)(g * 512 + jglob) * 64 + bglob];
    }

    for (int sl = 0; sl < 256; ++sl) {
        // poll producer flags for frame sl (16 contiguous flags per wave)
        if (l < 16) {
            const unsigned* fp = bar + half * 64 + kh * 16 + l;
            while (__hip_atomic_load(fp, __ATOMIC_RELAXED,
                                     __HIP_MEMORY_SCOPE_AGENT) < (unsigned)sl)
                __builtin_amdgcn_s_sleep(1);
        }
        if (tid == 256 && sl < 255) {
            while (__hip_atomic_load(&pre_cnt[sl + 1], __ATOMIC_RELAXED,
                                     __HIP_MEMORY_SCOPE_AGENT) < 16u)
                __builtin_amdgcn_s_sleep(1);
        }

        // A (h) fragment loads for (mt, kh): all AH, then all AL
        bf16x8 AH[4], AL[4];
        size_t fb = (size_t)sl * 32768 + (size_t)(mt * 16 + kh * 4) * 512 + (size_t)l * 8;
#pragma unroll
        for (int kt2 = 0; kt2 < 4; ++kt2)
            AH[kt2] = frag_load16(Xoh + fb + kt2 * 512);
#pragma unroll
        for (int kt2 = 0; kt2 < 4; ++kt2)
            AL[kt2] = frag_load16(Xol + fb + kt2 * 512);

        f32x4 acc0 = {0.f, 0.f, 0.f, 0.f};
        f32x4 acc1 = {0.f, 0.f, 0.f, 0.f};

        asm volatile("s_waitcnt vmcnt(4)" ::: "memory");   // AH ready
        __builtin_amdgcn_sched_barrier(0);
#pragma unroll
        for (int kt2 = 0; kt2 < 4; ++kt2) {
            acc0 = __builtin_amdgcn_mfma_f32_16x16x32_bf16(AH[kt2], BH[kt2][0], acc0, 0, 0, 0);
            acc1 = __builtin_amdgcn_mfma_f32_16x16x32_bf16(AH[kt2], BH[kt2][1], acc1, 0, 0, 0);
        }
        asm volatile("s_waitcnt vmcnt(0)" ::: "memory");   // AL ready
        __builtin_amdgcn_sched_barrier(0);
#pragma unroll
        for (int kt2 = 0; kt2 < 4; ++kt2) {
            acc0 = __builtin_amdgcn_mfma_f32_16x16x32_bf16(AL[kt2], BH[kt2][0], acc0, 0, 0, 0);
            acc1 = __builtin_amdgcn_mfma_f32_16x16x32_bf16(AL[kt2], BH[kt2][1], acc1, 0, 0, 0);
            acc0 = __builtin_amdgcn_mfma_f32_16x16x32_bf16(AH[kt2], BL[kt2][0], acc0, 0, 0, 0);
            acc1 = __builtin_amdgcn_mfma_f32_16x16x32_bf16(AH[kt2], BL[kt2][1], acc1, 0, 0, 0);
        }

        // dump partials: part[(kh*2+nt)*16 + n][b_local]
#pragma unroll
        for (int r = 0; r < 4; ++r) {
            int col = mq * 16 + (l >> 4) * 4 + r;
            part[((kh * 2 + 0) * 16 + (l & 15)) * 33 + col] = acc0[r];
            part[((kh * 2 + 1) * 16 + (l & 15)) * 33 + col] = acc1[r];
        }
        __syncthreads();    // (1)

        if (fin) {
            float z[4];
#pragma unroll
            for (int g = 0; g < 4; ++g) {
                float zz = pzv[g];
#pragma unroll
                for (int k2 = 0; k2 < 4; ++k2)
                    zz += part[((k2 * 2 + (g >> 1)) * 16 + (g & 1) * 8 + u8) * 33 + bl];
                z[g] = zz;
            }
            float ig = sigf(z[0]);
            float fg = sigf(z[1]);
            float gg = tanhfast(z[2]);
            float og = sigf(z[3]);
            float cn = fg * creg + ig * gg;
            float hn = og * tanhfast(cn);
            bool mk = maskv != 0;
            float ho = mk ? hn : hpre;
            creg = mk ? cn : creg;
            hpre = ho;
            if (writeX)
                xT32[((size_t)sl * DQ + jglob) * 64 + bglob] = ho;
            unsigned hi = f2bf(ho);
            unsigned lo = f2bf(ho - bf2f(hi));
            hlds[u8 * 32 + bl] = hi | (lo << 16);
        }
        __syncthreads();    // (2)

        // wave 7 (non-finisher): repack + coherent 16B stores + drain + flag
        if (w == 7) {
            int plane = l >> 5, b2 = l & 31;
            int bg = half * 32 + b2;
            unsigned v[8];
#pragma unroll
            for (int u = 0; u < 8; ++u) v[u] = hlds[u * 32 + b2];
            u32x4 d;
            if (plane == 0) {
#pragma unroll
                for (int i = 0; i < 4; ++i)
                    d[i] = (v[2 * i] & 0xffffu) | (v[2 * i + 1] << 16);
            } else {
#pragma unroll
                for (int i = 0; i < 4; ++i)
                    d[i] = (v[2 * i] >> 16) | (v[2 * i + 1] & 0xffff0000u);
            }
            size_t wi = (((size_t)(sl + 1) * 4 + (bg >> 4)) * 16 + (o >> 2)) * 512 +
                        ((o & 3) * 16 + (bg & 15)) * 8;
            unsigned short* dst = (plane ? Xol : Xoh) + wi;
            asm volatile("global_store_dwordx4 %0, %1, off sc0 sc1" :: "v"(dst), "v"(d));
            asm volatile("s_waitcnt vmcnt(0)" ::: "memory");
            if (l == 0) {
                unsigned* fdst = bar + half * 64 + o;
                unsigned fval = (unsigned)(sl + 1);
                asm volatile("global_store_dword %0, %1, off sc0 sc1" :: "v"(fdst), "v"(fval));
            }
        }

        // prefetch next step's finish operands (ordered after this step's spins)
        if (fin && sl < 255) {
            int t1 = flip ? (254 - sl) : (sl + 1);
            maskv = mask[bglob * TQ + t1];
#pragma unroll
            for (int g = 0; g < 4; ++g)
                pzv[g] = preF[((size_t)(sl + 1) * GQ + g * 512 + jglob) * 64 + bglob];
        }
    }
}

// ---------------- logits = x @ Wout + bout ----------------
__global__ __launch_bounds__(256) void k_out(const float* __restrict__ xT,
                                             const float* __restrict__ Wo,
                                             const float* __restrict__ bo,
                                             float* __restrict__ out) {
    __shared__ float WoL[64 * 64];
    int t = blockIdx.x;
    int tid = threadIdx.x;
    int b = tid & 63;
    int q = tid >> 6;
    float acc[16];
#pragma unroll
    for (int i = 0; i < 16; ++i) acc[i] = 0.f;

    for (int kc = 0; kc < 8; ++kc) {
        __syncthreads();
#pragma unroll
        for (int uu = 0; uu < 4; ++uu)
            *(float4*)&WoL[tid * 16 + uu * 4] =
                *(const float4*)&Wo[kc * 4096 + tid * 16 + uu * 4];
        __syncthreads();
        for (int kk = 0; kk < 64; ++kk) {
            float xv = xT[((size_t)t * DQ + kc * 64 + kk) * 64 + b];
#pragma unroll
            for (int uu = 0; uu < 4; ++uu) {
                float4 wv = *(const float4*)&WoL[kk * 64 + q * 16 + uu * 4];
                acc[uu * 4 + 0] += xv * wv.x;
                acc[uu * 4 + 1] += xv * wv.y;
                acc[uu * 4 + 2] += xv * wv.z;
                acc[uu * 4 + 3] += xv * wv.w;
            }
        }
    }
#pragma unroll
    for (int uu = 0; uu < 4; ++uu) {
        int n = q * 16 + uu * 4;
        float4 v = {acc[uu * 4 + 0] + bo[n + 0], acc[uu * 4 + 1] + bo[n + 1],
                    acc[uu * 4 + 2] + bo[n + 2], acc[uu * 4 + 3] + bo[n + 3]};
        *(float4*)&out[((size_t)(b * TQ + t)) * 64 + n] = v;
    }
}

extern "C" void kernel_launch(void* const* d_in, const int* in_sizes, int n_in,
                              void* d_out, int out_size, void* d_ws, size_t ws_size,
                              hipStream_t stream) {
    const int*   wid  = (const int*)d_in[0];
    const int*   pid  = (const int*)d_in[1];
    const int*   mask = (const int*)d_in[2];
    const float* emb  = (const float*)d_in[3];
    const float* Ws   = (const float*)d_in[4];
    const float* Us   = (const float*)d_in[5];
    const float* bs   = (const float*)d_in[6];
    const float* Wo   = (const float*)d_in[7];
    const float* bo   = (const float*)d_in[8];
    float* out = (float*)d_out;

    const size_t XFPLANE = (size_t)257 * 32768;      // shorts per plane
    char* p = (char*)d_ws;
    float* xRaw = (float*)p;                  p += 33554432;
    unsigned short* XFA = (unsigned short*)p; p += 2 * XFPLANE * 2;
    unsigned short* XFB = (unsigned short*)p; p += 2 * XFPLANE * 2;
    unsigned short* UFh = (unsigned short*)p; p += 8388608;
    unsigned short* UFl = (unsigned short*)p; p += 8388608;
    unsigned short* WFh = (unsigned short*)p; p += 8388608;
    unsigned short* WFl = (unsigned short*)p; p += 8388608;
    unsigned* bar = (unsigned*)p;             p += 8192;
    float* preF = (float*)p;                  // 256*2048*64*4 = 134217728

    k_convU<<<16384, 256, 0, stream>>>(Us, UFh, UFl);
    k_convW<<<16384, 256, 0, stream>>>(Ws, WFh, WFl);
    k_embed<<<dim3(TQ, 8), 256, 0, stream>>>(wid, pid, emb, xRaw);
    k_convX<<<32768, 256, 0, stream>>>(xRaw, XFA, XFA + XFPLANE);

    for (int layer = 0; layer < 4; ++layer) {
        int flip = layer & 1;
        int writeX = (layer == 3) ? 1 : 0;
        const float* bias = bs + (size_t)layer * GQ;
        const unsigned short* UFh_l = UFh + (size_t)layer * 1048576;
        const unsigned short* UFl_l = UFl + (size_t)layer * 1048576;
        const unsigned short* WFh_l = WFh + (size_t)layer * 1048576;
        const unsigned short* WFl_l = WFl + (size_t)layer * 1048576;
        unsigned short* Xi = (layer & 1) ? XFB : XFA;
        unsigned short* Xo = (layer & 1) ? XFA : XFB;

        hipMemsetAsync(Xo, 0, 65536, stream);                  // frame 0 hi
        hipMemsetAsync(Xo + XFPLANE, 0, 65536, stream);        // frame 0 lo
        hipMemsetAsync(bar, 0, 8192, stream);                  // flags + pre_cnt

        k_fused<<<256, 512, 0, stream>>>(UFh_l, UFl_l, WFh_l, WFl_l,
                                         Xi, Xi + XFPLANE, Xo, Xo + XFPLANE,
                                         preF, mask, bias, xRaw, bar,
                                         flip, writeX);
    }

    k_out<<<TQ, 256, 0, stream>>>(xRaw, Wo, bo, out);
}

// Round 11
// 3270.632 us; speedup vs baseline: 1.6882x; 1.6882x over previous
//
#include <hip/hip_runtime.h>
#include <math.h>

#define TQ 256
#define DQ 512
#define GQ 2048

typedef __attribute__((ext_vector_type(8))) short bf16x8;
typedef __attribute__((ext_vector_type(4))) float f32x4;
typedef __attribute__((ext_vector_type(4))) unsigned u32x4;

__device__ __forceinline__ unsigned f2bf(float x) {
    unsigned u = __builtin_bit_cast(unsigned, x);
    return (u + 0x7fffu + ((u >> 16) & 1u)) >> 16;
}
__device__ __forceinline__ float bf2f(unsigned s) {
    return __builtin_bit_cast(float, s << 16);
}
__device__ __forceinline__ float sigf(float x) { return 1.f / (1.f + __expf(-x)); }
__device__ __forceinline__ float tanhfast(float x) { return 1.f - 2.f / (__expf(2.f * x) + 1.f); }

// L1-bypass 16B load (frames are write-once per layer; L2 fills are fresh)
__device__ __forceinline__ bf16x8 frag_load16(const unsigned short* p) {
    bf16x8 r;
    asm volatile("global_load_dwordx4 %0, %1, off sc0" : "=v"(r) : "v"(p));
    return r;
}

// ---------------- embedding + predicate concat -> xRaw[t][d][b] --------------
__global__ __launch_bounds__(256) void k_embed(const int* __restrict__ wid,
                                               const int* __restrict__ pid,
                                               const float* __restrict__ emb,
                                               float* __restrict__ xT) {
    __shared__ float Ls[64][65];
    int t = blockIdx.x;
    int d0 = blockIdx.y * 64;
    int tid = threadIdx.x;
    int l = tid & 63;
    int grp = tid >> 6;
#pragma unroll 4
    for (int bb = 0; bb < 16; ++bb) {
        int b = grp * 16 + bb;
        int d = d0 + l;
        float v;
        if (d < 511) v = emb[(size_t)wid[b * TQ + t] * 511 + d];
        else         v = (float)pid[b * TQ + t];
        Ls[l][b] = v;
    }
    __syncthreads();
#pragma unroll 4
    for (int dd = 0; dd < 16; ++dd) {
        int dl = grp * 16 + dd;
        xT[((size_t)t * DQ + d0 + dl) * 64 + l] = Ls[dl][l];
    }
}

// ---------------- xRaw -> x fragments (layer-0 input) ------------------------
__global__ __launch_bounds__(256) void k_convX(const float* __restrict__ xT,
                                               unsigned short* __restrict__ Xh,
                                               unsigned short* __restrict__ Xl) {
    int idx = blockIdx.x * 256 + threadIdx.x;    // (t*512 + d)*64 + b
    int b = idx & 63;
    int d = (idx >> 6) & 511;
    int t = idx >> 15;
    float v = xT[idx];
    unsigned hi = f2bf(v);
    unsigned lo = f2bf(v - bf2f(hi));
    size_t wi = (((size_t)(1 + t) * 4 + (b >> 4)) * 16 + (d >> 5)) * 512 +
                (((d >> 3) & 3) * 16 + (b & 15)) * 8 + (d & 7);
    Xh[wi] = (unsigned short)hi;
    Xl[wi] = (unsigned short)lo;
}

// ---------------- W -> A-operand fragments (m = col) -------------------------
__global__ __launch_bounds__(256) void k_convW(const float* __restrict__ Ws,
                                               unsigned short* __restrict__ Wh,
                                               unsigned short* __restrict__ Wl) {
    int idx = blockIdx.x * 256 + threadIdx.x;    // (lay*512 + d)*2048 + c
    int c = idx & 2047;
    int d = (idx >> 11) & 511;
    int lay = idx >> 20;
    float v = Ws[idx];
    unsigned hi = f2bf(v);
    unsigned lo = f2bf(v - bf2f(hi));
    size_t wi = (((size_t)lay * 128 + (c >> 4)) * 16 + (d >> 5)) * 512 +
                (((d >> 3) & 3) * 16 + (c & 15)) * 8 + (d & 7);
    Wh[wi] = (unsigned short)hi;
    Wl[wi] = (unsigned short)lo;
}

// ---------------- U -> B-operand fragments (n = (g&1)*8 + jl) ----------------
__global__ __launch_bounds__(256) void k_convU(const float* __restrict__ Us,
                                               unsigned short* __restrict__ Uh,
                                               unsigned short* __restrict__ Ul) {
    int idx = blockIdx.x * 256 + threadIdx.x;    // (lay*512 + k)*2048 + c
    int c = idx & 2047;
    int k = (idx >> 11) & 511;
    int lay = idx >> 20;
    float v = Us[idx];
    unsigned hi = f2bf(v);
    unsigned lo = f2bf(v - bf2f(hi));
    int g = c >> 9;
    int o = (c >> 3) & 63;
    int jl = c & 7;
    int nt = g >> 1;
    int n = (g & 1) * 8 + jl;
    size_t wi = ((((size_t)lay * 64 + o) * 16 + (k >> 5)) * 2 + nt) * 512 +
                (((k >> 3) & 3) * 16 + n) * 8 + (k & 7);
    Uh[wi] = (unsigned short)hi;
    Ul[wi] = (unsigned short)lo;
}

// ---------------- fused layer kernel ----------------
// grid = 256 WGs x 512 thr. WG < 128: recurrence (o = wg>>1 owns 8 units,
// half = wg&1 owns 32 batch). WG >= 128: pre-producer (x@W tiles + per-sl flag).
// Flags are monotonic across layers: fbase = layer*256.
__global__ __launch_bounds__(512, 1) void k_fused(
    const unsigned short* __restrict__ Uh, const unsigned short* __restrict__ Ul,
    const unsigned short* __restrict__ Wh, const unsigned short* __restrict__ Wl,
    const unsigned short* __restrict__ Xih, const unsigned short* __restrict__ Xil,
    unsigned short* __restrict__ Xoh, unsigned short* __restrict__ Xol,
    float* __restrict__ preF, const int* __restrict__ mask,
    const float* __restrict__ bias, float* __restrict__ xT32,
    unsigned* __restrict__ bar, int flip, int writeX, unsigned fbase, unsigned ptgt)
{
    __shared__ char ldsraw[81920];     // force 1 WG/CU; union of roles
    int wg = blockIdx.x;
    int tid = threadIdx.x;
    int w = tid >> 6, l = tid & 63;
    unsigned* pre_cnt = bar + 1024;

    if (wg >= 128) {
        // ================= pre-producer role =================
        float* stage = (float*)ldsraw + w * (16 * 68);
        int q = wg - 128;
        for (int T = q; T < 4096; T += 128) {
            int sl = T >> 4, cg = T & 15;
            int t_in = flip ? (255 - sl) : sl;
            int ct = cg * 8 + w;
            size_t xb = (size_t)(1 + t_in) * 32768 + (size_t)l * 8;
            f32x4 acc[4];
            f32x4 zv = {0.f, 0.f, 0.f, 0.f};
#pragma unroll
            for (int bt = 0; bt < 4; ++bt) acc[bt] = zv;

#pragma unroll 2
            for (int kt = 0; kt < 16; ++kt) {
                size_t wa = ((size_t)ct * 16 + kt) * 512 + l * 8;
                bf16x8 ah = *(const bf16x8*)(Wh + wa);
                bf16x8 al = *(const bf16x8*)(Wl + wa);
                bf16x8 bh[4], bo[4];
#pragma unroll
                for (int bt = 0; bt < 4; ++bt) {
                    size_t a = xb + (size_t)(bt * 16 + kt) * 512;
                    bh[bt] = *(const bf16x8*)(Xih + a);
                    bo[bt] = *(const bf16x8*)(Xil + a);
                }
#pragma unroll
                for (int bt = 0; bt < 4; ++bt) {
                    acc[bt] = __builtin_amdgcn_mfma_f32_16x16x32_bf16(ah, bh[bt], acc[bt], 0, 0, 0);
                    acc[bt] = __builtin_amdgcn_mfma_f32_16x16x32_bf16(al, bh[bt], acc[bt], 0, 0, 0);
                    acc[bt] = __builtin_amdgcn_mfma_f32_16x16x32_bf16(ah, bo[bt], acc[bt], 0, 0, 0);
                }
            }
            // stage (wave-local) then 16B coherent stores
#pragma unroll
            for (int bt = 0; bt < 4; ++bt)
#pragma unroll
                for (int r = 0; r < 4; ++r)
                    stage[((l >> 4) * 4 + r) * 68 + bt * 16 + (l & 15)] = acc[bt][r];
#pragma unroll
            for (int p = 0; p < 4; ++p) {
                int cr = p * 4 + (l >> 4);
                float bv = bias[ct * 16 + cr];
                f32x4 v = *(f32x4*)&stage[cr * 68 + (l & 15) * 4];
                v[0] += bv; v[1] += bv; v[2] += bv; v[3] += bv;
                float* dst = &preF[((size_t)sl * GQ + ct * 16 + cr) * 64 + (l & 15) * 4];
                asm volatile("global_store_dwordx4 %0, %1, off sc0 sc1" :: "v"(dst), "v"(v));
            }
            __syncthreads();   // drains vmcnt for all waves
            if (tid == 0)
                __hip_atomic_fetch_add(&pre_cnt[sl], 1u, __ATOMIC_RELAXED,
                                       __HIP_MEMORY_SCOPE_AGENT);
        }
        return;
    }

    // ================= recurrence role =================
    int o = wg >> 1, half = wg & 1;
    int kh = w >> 1, mq = w & 1;
    int mt = half * 2 + mq;            // global 16-batch tile
    float* part = (float*)ldsraw;      // [128][33]
    unsigned* hlds = (unsigned*)(ldsraw + 16896);  // [8][32]

    // resident U fragments (hi + lo) for this wave's k-quarter
    bf16x8 BH[4][2], BL[4][2];
#pragma unroll
    for (int kt2 = 0; kt2 < 4; ++kt2)
#pragma unroll
        for (int nt = 0; nt < 2; ++nt) {
            size_t a = (((size_t)o * 16 + kh * 4 + kt2) * 2 + nt) * 512 + l * 8;
            BH[kt2][nt] = *(const bf16x8*)(Uh + a);
            BL[kt2][nt] = *(const bf16x8*)(Ul + a);
        }

    int u8 = (tid >> 5) & 7;
    int bl = tid & 31;
    int jglob = o * 8 + u8;
    int bglob = half * 32 + bl;
    bool fin = tid < 256;

    float creg = 0.f, hpre = 0.f;
    float pzv[4];
    int maskv = 0;

    // prologue: wait for pre of sl=0, then prefetch finish operands
    if (tid == 0) {
        while (__hip_atomic_load(&pre_cnt[0], __ATOMIC_RELAXED,
                                 __HIP_MEMORY_SCOPE_AGENT) < ptgt)
            __builtin_amdgcn_s_sleep(1);
    }
    __syncthreads();
    if (fin) {
        int t0 = flip ? 255 : 0;
        maskv = mask[bglob * TQ + t0];
#pragma unroll
        for (int g = 0; g < 4; ++g)
            pzv[g] = preF[(size_t)(g * 512 + jglob) * 64 + bglob];
    }

    for (int sl = 0; sl < 256; ++sl) {
        // poll producer flags for frame sl (16 producers per wave, 1 flag/sector)
        if (l < 16) {
            const unsigned* fp = bar + ((((kh * 16 + l) << 1) | half) << 3);
            while (__hip_atomic_load(fp, __ATOMIC_RELAXED,
                                     __HIP_MEMORY_SCOPE_AGENT) < fbase + (unsigned)sl)
                __builtin_amdgcn_s_sleep(1);
        }
        if (tid == 256 && sl < 255) {
            while (__hip_atomic_load(&pre_cnt[sl + 1], __ATOMIC_RELAXED,
                                     __HIP_MEMORY_SCOPE_AGENT) < ptgt)
                __builtin_amdgcn_s_sleep(1);
        }

        // A (h) fragment loads for (mt, kh): all AH, then all AL
        bf16x8 AH[4], AL[4];
        size_t fb = (size_t)sl * 32768 + (size_t)(mt * 16 + kh * 4) * 512 + (size_t)l * 8;
#pragma unroll
        for (int kt2 = 0; kt2 < 4; ++kt2)
            AH[kt2] = frag_load16(Xoh + fb + kt2 * 512);
#pragma unroll
        for (int kt2 = 0; kt2 < 4; ++kt2)
            AL[kt2] = frag_load16(Xol + fb + kt2 * 512);

        f32x4 acc0 = {0.f, 0.f, 0.f, 0.f};
        f32x4 acc1 = {0.f, 0.f, 0.f, 0.f};

        asm volatile("s_waitcnt vmcnt(4)" ::: "memory");   // AH ready
        __builtin_amdgcn_sched_barrier(0);
#pragma unroll
        for (int kt2 = 0; kt2 < 4; ++kt2) {
            acc0 = __builtin_amdgcn_mfma_f32_16x16x32_bf16(AH[kt2], BH[kt2][0], acc0, 0, 0, 0);
            acc1 = __builtin_amdgcn_mfma_f32_16x16x32_bf16(AH[kt2], BH[kt2][1], acc1, 0, 0, 0);
        }
        asm volatile("s_waitcnt vmcnt(0)" ::: "memory");   // AL ready
        __builtin_amdgcn_sched_barrier(0);
#pragma unroll
        for (int kt2 = 0; kt2 < 4; ++kt2) {
            acc0 = __builtin_amdgcn_mfma_f32_16x16x32_bf16(AL[kt2], BH[kt2][0], acc0, 0, 0, 0);
            acc1 = __builtin_amdgcn_mfma_f32_16x16x32_bf16(AL[kt2], BH[kt2][1], acc1, 0, 0, 0);
            acc0 = __builtin_amdgcn_mfma_f32_16x16x32_bf16(AH[kt2], BL[kt2][0], acc0, 0, 0, 0);
            acc1 = __builtin_amdgcn_mfma_f32_16x16x32_bf16(AH[kt2], BL[kt2][1], acc1, 0, 0, 0);
        }

        // dump partials: part[(kh*2+nt)*16 + n][b_local]
#pragma unroll
        for (int r = 0; r < 4; ++r) {
            int col = mq * 16 + (l >> 4) * 4 + r;
            part[((kh * 2 + 0) * 16 + (l & 15)) * 33 + col] = acc0[r];
            part[((kh * 2 + 1) * 16 + (l & 15)) * 33 + col] = acc1[r];
        }
        __syncthreads();    // (1)

        if (fin) {
            float z[4];
#pragma unroll
            for (int g = 0; g < 4; ++g) {
                float zz = pzv[g];
#pragma unroll
                for (int k2 = 0; k2 < 4; ++k2)
                    zz += part[((k2 * 2 + (g >> 1)) * 16 + (g & 1) * 8 + u8) * 33 + bl];
                z[g] = zz;
            }
            float ig = sigf(z[0]);
            float fg = sigf(z[1]);
            float gg = tanhfast(z[2]);
            float og = sigf(z[3]);
            float cn = fg * creg + ig * gg;
            float hn = og * tanhfast(cn);
            bool mk = maskv != 0;
            float ho = mk ? hn : hpre;
            creg = mk ? cn : creg;
            hpre = ho;
            if (writeX)
                xT32[((size_t)sl * DQ + jglob) * 64 + bglob] = ho;
            unsigned hi = f2bf(ho);
            unsigned lo = f2bf(ho - bf2f(hi));
            hlds[u8 * 32 + bl] = hi | (lo << 16);
        }
        __syncthreads();    // (2)

        // wave 7 (non-finisher): repack + coherent 16B stores + drain + flag
        if (w == 7) {
            int plane = l >> 5, b2 = l & 31;
            int bg = half * 32 + b2;
            unsigned v[8];
#pragma unroll
            for (int u = 0; u < 8; ++u) v[u] = hlds[u * 32 + b2];
            u32x4 d;
            if (plane == 0) {
#pragma unroll
                for (int i = 0; i < 4; ++i)
                    d[i] = (v[2 * i] & 0xffffu) | (v[2 * i + 1] << 16);
            } else {
#pragma unroll
                for (int i = 0; i < 4; ++i)
                    d[i] = (v[2 * i] >> 16) | (v[2 * i + 1] & 0xffff0000u);
            }
            size_t wi = (((size_t)(sl + 1) * 4 + (bg >> 4)) * 16 + (o >> 2)) * 512 +
                        ((o & 3) * 16 + (bg & 15)) * 8;
            unsigned short* dst = (plane ? Xol : Xoh) + wi;
            asm volatile("global_store_dwordx4 %0, %1, off sc0 sc1" :: "v"(dst), "v"(d));
            asm volatile("s_waitcnt vmcnt(0)" ::: "memory");
            if (l == 0)
                __hip_atomic_store(&bar[wg * 8], fbase + (unsigned)(sl + 1),
                                   __ATOMIC_RELAXED, __HIP_MEMORY_SCOPE_AGENT);
        }

        // prefetch next step's finish operands (ordered after this step's spins)
        if (fin && sl < 255) {
            int t1 = flip ? (254 - sl) : (sl + 1);
            maskv = mask[bglob * TQ + t1];
#pragma unroll
            for (int g = 0; g < 4; ++g)
                pzv[g] = preF[((size_t)(sl + 1) * GQ + g * 512 + jglob) * 64 + bglob];
        }
    }
}

// ---------------- logits = x @ Wout + bout ----------------
__global__ __launch_bounds__(256) void k_out(const float* __restrict__ xT,
                                             const float* __restrict__ Wo,
                                             const float* __restrict__ bo,
                                             float* __restrict__ out) {
    __shared__ float WoL[64 * 64];
    int t = blockIdx.x;
    int tid = threadIdx.x;
    int b = tid & 63;
    int q = tid >> 6;
    float acc[16];
#pragma unroll
    for (int i = 0; i < 16; ++i) acc[i] = 0.f;

    for (int kc = 0; kc < 8; ++kc) {
        __syncthreads();
#pragma unroll
        for (int uu = 0; uu < 4; ++uu)
            *(float4*)&WoL[tid * 16 + uu * 4] =
                *(const float4*)&Wo[kc * 4096 + tid * 16 + uu * 4];
        __syncthreads();
        for (int kk = 0; kk < 64; ++kk) {
            float xv = xT[((size_t)t * DQ + kc * 64 + kk) * 64 + b];
#pragma unroll
            for (int uu = 0; uu < 4; ++uu) {
                float4 wv = *(const float4*)&WoL[kk * 64 + q * 16 + uu * 4];
                acc[uu * 4 + 0] += xv * wv.x;
                acc[uu * 4 + 1] += xv * wv.y;
                acc[uu * 4 + 2] += xv * wv.z;
                acc[uu * 4 + 3] += xv * wv.w;
            }
        }
    }
#pragma unroll
    for (int uu = 0; uu < 4; ++uu) {
        int n = q * 16 + uu * 4;
        float4 v = {acc[uu * 4 + 0] + bo[n + 0], acc[uu * 4 + 1] + bo[n + 1],
                    acc[uu * 4 + 2] + bo[n + 2], acc[uu * 4 + 3] + bo[n + 3]};
        *(float4*)&out[((size_t)(b * TQ + t)) * 64 + n] = v;
    }
}

extern "C" void kernel_launch(void* const* d_in, const int* in_sizes, int n_in,
                              void* d_out, int out_size, void* d_ws, size_t ws_size,
                              hipStream_t stream) {
    const int*   wid  = (const int*)d_in[0];
    const int*   pid  = (const int*)d_in[1];
    const int*   mask = (const int*)d_in[2];
    const float* emb  = (const float*)d_in[3];
    const float* Ws   = (const float*)d_in[4];
    const float* Us   = (const float*)d_in[5];
    const float* bs   = (const float*)d_in[6];
    const float* Wo   = (const float*)d_in[7];
    const float* bo   = (const float*)d_in[8];
    float* out = (float*)d_out;

    const size_t XFPLANE = (size_t)257 * 32768;      // shorts per plane
    char* p = (char*)d_ws;
    float* xRaw = (float*)p;                  p += 33554432;
    unsigned short* XFA = (unsigned short*)p; p += 2 * XFPLANE * 2;
    unsigned short* XFB = (unsigned short*)p; p += 2 * XFPLANE * 2;
    unsigned short* UFh = (unsigned short*)p; p += 8388608;
    unsigned short* UFl = (unsigned short*)p; p += 8388608;
    unsigned short* WFh = (unsigned short*)p; p += 8388608;
    unsigned short* WFl = (unsigned short*)p; p += 8388608;
    unsigned* bar = (unsigned*)p;             p += 8192;
    float* preF = (float*)p;                  // 256*2048*64*4 = 134217728

    // one-time zeroing: flags/pre_cnt + frame 0 of both exchange buffers
    hipMemsetAsync(bar, 0, 8192, stream);
    hipMemsetAsync(XFA, 0, 65536, stream);
    hipMemsetAsync(XFA + XFPLANE, 0, 65536, stream);
    hipMemsetAsync(XFB, 0, 65536, stream);
    hipMemsetAsync(XFB + XFPLANE, 0, 65536, stream);

    k_convU<<<16384, 256, 0, stream>>>(Us, UFh, UFl);
    k_convW<<<16384, 256, 0, stream>>>(Ws, WFh, WFl);
    k_embed<<<dim3(TQ, 8), 256, 0, stream>>>(wid, pid, emb, xRaw);
    k_convX<<<32768, 256, 0, stream>>>(xRaw, XFA, XFA + XFPLANE);

    for (int layer = 0; layer < 4; ++layer) {
        int flip = layer & 1;
        int writeX = (layer == 3) ? 1 : 0;
        const float* bias = bs + (size_t)layer * GQ;
        const unsigned short* UFh_l = UFh + (size_t)layer * 1048576;
        const unsigned short* UFl_l = UFl + (size_t)layer * 1048576;
        const unsigned short* WFh_l = WFh + (size_t)layer * 1048576;
        const unsigned short* WFl_l = WFl + (size_t)layer * 1048576;
        unsigned short* Xi = (layer & 1) ? XFB : XFA;
        unsigned short* Xo = (layer & 1) ? XFA : XFB;

        k_fused<<<256, 512, 0, stream>>>(UFh_l, UFl_l, WFh_l, WFl_l,
                                         Xi, Xi + XFPLANE, Xo, Xo + XFPLANE,
                                         preF, mask, bias, xRaw, bar,
                                         flip, writeX,
                                         (unsigned)(layer * 256),
                                         (unsigned)(16 * (layer + 1)));
    }

    k_out<<<TQ, 256, 0, stream>>>(xRaw, Wo, bo, out);
}

// Round 12
// 3189.112 us; speedup vs baseline: 1.7314x; 1.0256x over previous
//
#include <hip/hip_runtime.h>
#include <math.h>

#define TQ 256
#define DQ 512
#define GQ 2048

typedef __attribute__((ext_vector_type(8))) short bf16x8;
typedef __attribute__((ext_vector_type(4))) float f32x4;
typedef __attribute__((ext_vector_type(4))) unsigned u32x4;

__device__ __forceinline__ unsigned f2bf(float x) {
    unsigned u = __builtin_bit_cast(unsigned, x);
    return (u + 0x7fffu + ((u >> 16) & 1u)) >> 16;
}
__device__ __forceinline__ float bf2f(unsigned s) {
    return __builtin_bit_cast(float, s << 16);
}
__device__ __forceinline__ float sigf(float x) { return 1.f / (1.f + __expf(-x)); }
__device__ __forceinline__ float tanhfast(float x) { return 1.f - 2.f / (__expf(2.f * x) + 1.f); }

// L1-bypass 16B load (frames are write-once per layer; L2 fills are fresh)
__device__ __forceinline__ bf16x8 frag_load16(const unsigned short* p) {
    bf16x8 r;
    asm volatile("global_load_dwordx4 %0, %1, off sc0" : "=v"(r) : "v"(p));
    return r;
}

// ---------------- embedding + predicate concat -> xRaw[t][d][b] --------------
__global__ __launch_bounds__(256) void k_embed(const int* __restrict__ wid,
                                               const int* __restrict__ pid,
                                               const float* __restrict__ emb,
                                               float* __restrict__ xT) {
    __shared__ float Ls[64][65];
    int t = blockIdx.x;
    int d0 = blockIdx.y * 64;
    int tid = threadIdx.x;
    int l = tid & 63;
    int grp = tid >> 6;
#pragma unroll 4
    for (int bb = 0; bb < 16; ++bb) {
        int b = grp * 16 + bb;
        int d = d0 + l;
        float v;
        if (d < 511) v = emb[(size_t)wid[b * TQ + t] * 511 + d];
        else         v = (float)pid[b * TQ + t];
        Ls[l][b] = v;
    }
    __syncthreads();
#pragma unroll 4
    for (int dd = 0; dd < 16; ++dd) {
        int dl = grp * 16 + dd;
        xT[((size_t)t * DQ + d0 + dl) * 64 + l] = Ls[dl][l];
    }
}

// ---------------- xRaw -> x fragments (layer-0 input) ------------------------
__global__ __launch_bounds__(256) void k_convX(const float* __restrict__ xT,
                                               unsigned short* __restrict__ Xh,
                                               unsigned short* __restrict__ Xl) {
    int idx = blockIdx.x * 256 + threadIdx.x;    // (t*512 + d)*64 + b
    int b = idx & 63;
    int d = (idx >> 6) & 511;
    int t = idx >> 15;
    float v = xT[idx];
    unsigned hi = f2bf(v);
    unsigned lo = f2bf(v - bf2f(hi));
    size_t wi = (((size_t)(1 + t) * 4 + (b >> 4)) * 16 + (d >> 5)) * 512 +
                (((d >> 3) & 3) * 16 + (b & 15)) * 8 + (d & 7);
    Xh[wi] = (unsigned short)hi;
    Xl[wi] = (unsigned short)lo;
}

// ---------------- W -> A-operand fragments (m = col) -------------------------
__global__ __launch_bounds__(256) void k_convW(const float* __restrict__ Ws,
                                               unsigned short* __restrict__ Wh,
                                               unsigned short* __restrict__ Wl) {
    int idx = blockIdx.x * 256 + threadIdx.x;    // (lay*512 + d)*2048 + c
    int c = idx & 2047;
    int d = (idx >> 11) & 511;
    int lay = idx >> 20;
    float v = Ws[idx];
    unsigned hi = f2bf(v);
    unsigned lo = f2bf(v - bf2f(hi));
    size_t wi = (((size_t)lay * 128 + (c >> 4)) * 16 + (d >> 5)) * 512 +
                (((d >> 3) & 3) * 16 + (c & 15)) * 8 + (d & 7);
    Wh[wi] = (unsigned short)hi;
    Wl[wi] = (unsigned short)lo;
}

// ---------------- U -> B-operand fragments (n = (g&1)*8 + jl) ----------------
__global__ __launch_bounds__(256) void k_convU(const float* __restrict__ Us,
                                               unsigned short* __restrict__ Uh,
                                               unsigned short* __restrict__ Ul) {
    int idx = blockIdx.x * 256 + threadIdx.x;    // (lay*512 + k)*2048 + c
    int c = idx & 2047;
    int k = (idx >> 11) & 511;
    int lay = idx >> 20;
    float v = Us[idx];
    unsigned hi = f2bf(v);
    unsigned lo = f2bf(v - bf2f(hi));
    int g = c >> 9;
    int o = (c >> 3) & 63;
    int jl = c & 7;
    int nt = g >> 1;
    int n = (g & 1) * 8 + jl;
    size_t wi = ((((size_t)lay * 64 + o) * 16 + (k >> 5)) * 2 + nt) * 512 +
                (((k >> 3) & 3) * 16 + n) * 8 + (k & 7);
    Uh[wi] = (unsigned short)hi;
    Ul[wi] = (unsigned short)lo;
}

// ---------------- fused layer kernel ----------------
// grid = 256 WGs x 512 thr. WG < 128: recurrence (o = wg>>1 owns 8 units,
// half = wg&1 owns 32 batch). WG >= 128: pre-producer (x@W tiles + per-sl flag).
// Flags are monotonic across layers: fbase = layer*256.
__global__ __launch_bounds__(512, 1) void k_fused(
    const unsigned short* __restrict__ Uh, const unsigned short* __restrict__ Ul,
    const unsigned short* __restrict__ Wh, const unsigned short* __restrict__ Wl,
    const unsigned short* __restrict__ Xih, const unsigned short* __restrict__ Xil,
    unsigned short* __restrict__ Xoh, unsigned short* __restrict__ Xol,
    float* __restrict__ preF, const int* __restrict__ mask,
    const float* __restrict__ bias, float* __restrict__ xT32,
    unsigned* __restrict__ bar, int flip, int writeX, unsigned fbase, unsigned ptgt)
{
    __shared__ char ldsraw[81920];     // force 1 WG/CU; union of roles
    int wg = blockIdx.x;
    int tid = threadIdx.x;
    int w = tid >> 6, l = tid & 63;
    unsigned* pre_cnt = bar + 1024;

    if (wg >= 128) {
        // ================= pre-producer role =================
        float* stage = (float*)ldsraw + w * (16 * 68);
        int q = wg - 128;
        for (int T = q; T < 4096; T += 128) {
            int sl = T >> 4, cg = T & 15;
            int t_in = flip ? (255 - sl) : sl;
            int ct = cg * 8 + w;
            size_t xb = (size_t)(1 + t_in) * 32768 + (size_t)l * 8;
            f32x4 acc[4];
            f32x4 zv = {0.f, 0.f, 0.f, 0.f};
#pragma unroll
            for (int bt = 0; bt < 4; ++bt) acc[bt] = zv;

#pragma unroll 2
            for (int kt = 0; kt < 16; ++kt) {
                size_t wa = ((size_t)ct * 16 + kt) * 512 + l * 8;
                bf16x8 ah = *(const bf16x8*)(Wh + wa);
                bf16x8 al = *(const bf16x8*)(Wl + wa);
                bf16x8 bh[4], bo[4];
#pragma unroll
                for (int bt = 0; bt < 4; ++bt) {
                    size_t a = xb + (size_t)(bt * 16 + kt) * 512;
                    bh[bt] = *(const bf16x8*)(Xih + a);
                    bo[bt] = *(const bf16x8*)(Xil + a);
                }
#pragma unroll
                for (int bt = 0; bt < 4; ++bt) {
                    acc[bt] = __builtin_amdgcn_mfma_f32_16x16x32_bf16(ah, bh[bt], acc[bt], 0, 0, 0);
                    acc[bt] = __builtin_amdgcn_mfma_f32_16x16x32_bf16(al, bh[bt], acc[bt], 0, 0, 0);
                    acc[bt] = __builtin_amdgcn_mfma_f32_16x16x32_bf16(ah, bo[bt], acc[bt], 0, 0, 0);
                }
            }
            // stage (wave-local) then 16B coherent stores
#pragma unroll
            for (int bt = 0; bt < 4; ++bt)
#pragma unroll
                for (int r = 0; r < 4; ++r)
                    stage[((l >> 4) * 4 + r) * 68 + bt * 16 + (l & 15)] = acc[bt][r];
#pragma unroll
            for (int p = 0; p < 4; ++p) {
                int cr = p * 4 + (l >> 4);
                float bv = bias[ct * 16 + cr];
                f32x4 v = *(f32x4*)&stage[cr * 68 + (l & 15) * 4];
                v[0] += bv; v[1] += bv; v[2] += bv; v[3] += bv;
                float* dst = &preF[((size_t)sl * GQ + ct * 16 + cr) * 64 + (l & 15) * 4];
                asm volatile("global_store_dwordx4 %0, %1, off sc0 sc1" :: "v"(dst), "v"(v));
            }
            __syncthreads();   // drains vmcnt for all waves
            if (tid == 0)
                __hip_atomic_fetch_add(&pre_cnt[sl], 1u, __ATOMIC_RELAXED,
                                       __HIP_MEMORY_SCOPE_AGENT);
        }
        return;
    }

    // ================= recurrence role =================
    int o = wg >> 1, half = wg & 1;
    int kh = w >> 1, mq = w & 1;
    int mt = half * 2 + mq;            // global 16-batch tile
    float* part = (float*)ldsraw;      // [128][33]
    unsigned* hlds = (unsigned*)(ldsraw + 16896);  // [8][32]

    // resident U fragments (hi + lo) for this wave's k-quarter
    bf16x8 BH[4][2], BL[4][2];
#pragma unroll
    for (int kt2 = 0; kt2 < 4; ++kt2)
#pragma unroll
        for (int nt = 0; nt < 2; ++nt) {
            size_t a = (((size_t)o * 16 + kh * 4 + kt2) * 2 + nt) * 512 + l * 8;
            BH[kt2][nt] = *(const bf16x8*)(Uh + a);
            BL[kt2][nt] = *(const bf16x8*)(Ul + a);
        }

    int u8 = (tid >> 5) & 7;
    int bl = tid & 31;
    int jglob = o * 8 + u8;
    int bglob = half * 32 + bl;
    bool fin = tid < 256;

    float creg = 0.f, hpre = 0.f;
    float pzv[4];
    int maskv = 0;

    // prologue: wait for pre of sl=0, then prefetch finish operands
    if (tid == 0) {
        while (__hip_atomic_load(&pre_cnt[0], __ATOMIC_RELAXED,
                                 __HIP_MEMORY_SCOPE_AGENT) < ptgt)
            __builtin_amdgcn_s_sleep(1);
    }
    __syncthreads();
    if (fin) {
        int t0 = flip ? 255 : 0;
        maskv = mask[bglob * TQ + t0];
#pragma unroll
        for (int g = 0; g < 4; ++g)
            pzv[g] = preF[(size_t)(g * 512 + jglob) * 64 + bglob];
    }

    for (int sl = 0; sl < 256; ++sl) {
        // poll producer flags for frame sl (16 producers per wave, 1 flag/sector)
        if (l < 16) {
            const unsigned* fp = bar + ((((kh * 16 + l) << 1) | half) << 3);
            while (__hip_atomic_load(fp, __ATOMIC_RELAXED,
                                     __HIP_MEMORY_SCOPE_AGENT) < fbase + (unsigned)sl)
                __builtin_amdgcn_s_sleep(1);
        }
        if (tid == 256 && sl < 255) {
            while (__hip_atomic_load(&pre_cnt[sl + 1], __ATOMIC_RELAXED,
                                     __HIP_MEMORY_SCOPE_AGENT) < ptgt)
                __builtin_amdgcn_s_sleep(1);
        }

        // A (h) fragment loads for (mt, kh)
        bf16x8 AH[4], AL[4];
        size_t fb = (size_t)sl * 32768 + (size_t)(mt * 16 + kh * 4) * 512 + (size_t)l * 8;
#pragma unroll
        for (int kt2 = 0; kt2 < 4; ++kt2) {
            AH[kt2] = frag_load16(Xoh + fb + kt2 * 512);
            AL[kt2] = frag_load16(Xol + fb + kt2 * 512);
        }
        asm volatile("s_waitcnt vmcnt(0)" ::: "memory");
        __builtin_amdgcn_sched_barrier(0);

        f32x4 acc0 = {0.f, 0.f, 0.f, 0.f};
        f32x4 acc1 = {0.f, 0.f, 0.f, 0.f};
#pragma unroll
        for (int kt2 = 0; kt2 < 4; ++kt2) {
            acc0 = __builtin_amdgcn_mfma_f32_16x16x32_bf16(AH[kt2], BH[kt2][0], acc0, 0, 0, 0);
            acc1 = __builtin_amdgcn_mfma_f32_16x16x32_bf16(AH[kt2], BH[kt2][1], acc1, 0, 0, 0);
            acc0 = __builtin_amdgcn_mfma_f32_16x16x32_bf16(AL[kt2], BH[kt2][0], acc0, 0, 0, 0);
            acc1 = __builtin_amdgcn_mfma_f32_16x16x32_bf16(AL[kt2], BH[kt2][1], acc1, 0, 0, 0);
            acc0 = __builtin_amdgcn_mfma_f32_16x16x32_bf16(AH[kt2], BL[kt2][0], acc0, 0, 0, 0);
            acc1 = __builtin_amdgcn_mfma_f32_16x16x32_bf16(AH[kt2], BL[kt2][1], acc1, 0, 0, 0);
        }

        // dump partials: part[(kh*2+nt)*16 + n][b_local]
#pragma unroll
        for (int r = 0; r < 4; ++r) {
            int col = mq * 16 + (l >> 4) * 4 + r;
            part[((kh * 2 + 0) * 16 + (l & 15)) * 33 + col] = acc0[r];
            part[((kh * 2 + 1) * 16 + (l & 15)) * 33 + col] = acc1[r];
        }
        __syncthreads();    // (1)

        if (fin) {
            float z[4];
#pragma unroll
            for (int g = 0; g < 4; ++g) {
                float zz = pzv[g];
#pragma unroll
                for (int k2 = 0; k2 < 4; ++k2)
                    zz += part[((k2 * 2 + (g >> 1)) * 16 + (g & 1) * 8 + u8) * 33 + bl];
                z[g] = zz;
            }
            float ig = sigf(z[0]);
            float fg = sigf(z[1]);
            float gg = tanhfast(z[2]);
            float og = sigf(z[3]);
            float cn = fg * creg + ig * gg;
            float hn = og * tanhfast(cn);
            bool mk = maskv != 0;
            float ho = mk ? hn : hpre;
            creg = mk ? cn : creg;
            hpre = ho;
            if (writeX)
                xT32[((size_t)sl * DQ + jglob) * 64 + bglob] = ho;
            unsigned hi = f2bf(ho);
            unsigned lo = f2bf(ho - bf2f(hi));
            hlds[u8 * 32 + bl] = hi | (lo << 16);
        }
        __syncthreads();    // (2)

        // wave 7 (non-finisher): repack + coherent 16B stores + drain + flag
        if (w == 7) {
            int plane = l >> 5, b2 = l & 31;
            int bg = half * 32 + b2;
            unsigned v[8];
#pragma unroll
            for (int u = 0; u < 8; ++u) v[u] = hlds[u * 32 + b2];
            u32x4 d;
            if (plane == 0) {
#pragma unroll
                for (int i = 0; i < 4; ++i)
                    d[i] = (v[2 * i] & 0xffffu) | (v[2 * i + 1] << 16);
            } else {
#pragma unroll
                for (int i = 0; i < 4; ++i)
                    d[i] = (v[2 * i] >> 16) | (v[2 * i + 1] & 0xffff0000u);
            }
            size_t wi = (((size_t)(sl + 1) * 4 + (bg >> 4)) * 16 + (o >> 2)) * 512 +
                        ((o & 3) * 16 + (bg & 15)) * 8;
            unsigned short* dst = (plane ? Xol : Xoh) + wi;
            asm volatile("global_store_dwordx4 %0, %1, off sc0 sc1" :: "v"(dst), "v"(d));
            asm volatile("s_waitcnt vmcnt(0)" ::: "memory");
            if (l == 0)
                __hip_atomic_store(&bar[wg * 8], fbase + (unsigned)(sl + 1),
                                   __ATOMIC_RELAXED, __HIP_MEMORY_SCOPE_AGENT);
        }

        // prefetch next step's finish operands (ordered after this step's spins)
        if (fin && sl < 255) {
            int t1 = flip ? (254 - sl) : (sl + 1);
            maskv = mask[bglob * TQ + t1];
#pragma unroll
            for (int g = 0; g < 4; ++g)
                pzv[g] = preF[((size_t)(sl + 1) * GQ + g * 512 + jglob) * 64 + bglob];
        }
    }
}

// ---------------- logits = x @ Wout + bout ----------------
__global__ __launch_bounds__(256) void k_out(const float* __restrict__ xT,
                                             const float* __restrict__ Wo,
                                             const float* __restrict__ bo,
                                             float* __restrict__ out) {
    __shared__ float WoL[64 * 64];
    int t = blockIdx.x;
    int tid = threadIdx.x;
    int b = tid & 63;
    int q = tid >> 6;
    float acc[16];
#pragma unroll
    for (int i = 0; i < 16; ++i) acc[i] = 0.f;

    for (int kc = 0; kc < 8; ++kc) {
        __syncthreads();
#pragma unroll
        for (int uu = 0; uu < 4; ++uu)
            *(float4*)&WoL[tid * 16 + uu * 4] =
                *(const float4*)&Wo[kc * 4096 + tid * 16 + uu * 4];
        __syncthreads();
        for (int kk = 0; kk < 64; ++kk) {
            float xv = xT[((size_t)t * DQ + kc * 64 + kk) * 64 + b];
#pragma unroll
            for (int uu = 0; uu < 4; ++uu) {
                float4 wv = *(const float4*)&WoL[kk * 64 + q * 16 + uu * 4];
                acc[uu * 4 + 0] += xv * wv.x;
                acc[uu * 4 + 1] += xv * wv.y;
                acc[uu * 4 + 2] += xv * wv.z;
                acc[uu * 4 + 3] += xv * wv.w;
            }
        }
    }
#pragma unroll
    for (int uu = 0; uu < 4; ++uu) {
        int n = q * 16 + uu * 4;
        float4 v = {acc[uu * 4 + 0] + bo[n + 0], acc[uu * 4 + 1] + bo[n + 1],
                    acc[uu * 4 + 2] + bo[n + 2], acc[uu * 4 + 3] + bo[n + 3]};
        *(float4*)&out[((size_t)(b * TQ + t)) * 64 + n] = v;
    }
}

extern "C" void kernel_launch(void* const* d_in, const int* in_sizes, int n_in,
                              void* d_out, int out_size, void* d_ws, size_t ws_size,
                              hipStream_t stream) {
    const int*   wid  = (const int*)d_in[0];
    const int*   pid  = (const int*)d_in[1];
    const int*   mask = (const int*)d_in[2];
    const float* emb  = (const float*)d_in[3];
    const float* Ws   = (const float*)d_in[4];
    const float* Us   = (const float*)d_in[5];
    const float* bs   = (const float*)d_in[6];
    const float* Wo   = (const float*)d_in[7];
    const float* bo   = (const float*)d_in[8];
    float* out = (float*)d_out;

    const size_t XFPLANE = (size_t)257 * 32768;      // shorts per plane
    char* p = (char*)d_ws;
    float* xRaw = (float*)p;                  p += 33554432;
    unsigned short* XFA = (unsigned short*)p; p += 2 * XFPLANE * 2;
    unsigned short* XFB = (unsigned short*)p; p += 2 * XFPLANE * 2;
    unsigned short* UFh = (unsigned short*)p; p += 8388608;
    unsigned short* UFl = (unsigned short*)p; p += 8388608;
    unsigned short* WFh = (unsigned short*)p; p += 8388608;
    unsigned short* WFl = (unsigned short*)p; p += 8388608;
    unsigned* bar = (unsigned*)p;             p += 8192;
    float* preF = (float*)p;                  // 256*2048*64*4 = 134217728

    // one-time zeroing: flags/pre_cnt + frame 0 of both exchange buffers
    hipMemsetAsync(bar, 0, 8192, stream);
    hipMemsetAsync(XFA, 0, 65536, stream);
    hipMemsetAsync(XFA + XFPLANE, 0, 65536, stream);
    hipMemsetAsync(XFB, 0, 65536, stream);
    hipMemsetAsync(XFB + XFPLANE, 0, 65536, stream);

    k_convU<<<16384, 256, 0, stream>>>(Us, UFh, UFl);
    k_convW<<<16384, 256, 0, stream>>>(Ws, WFh, WFl);
    k_embed<<<dim3(TQ, 8), 256, 0, stream>>>(wid, pid, emb, xRaw);
    k_convX<<<32768, 256, 0, stream>>>(xRaw, XFA, XFA + XFPLANE);

    for (int layer = 0; layer < 4; ++layer) {
        int flip = layer & 1;
        int writeX = (layer == 3) ? 1 : 0;
        const float* bias = bs + (size_t)layer * GQ;
        const unsigned short* UFh_l = UFh + (size_t)layer * 1048576;
        const unsigned short* UFl_l = UFl + (size_t)layer * 1048576;
        const unsigned short* WFh_l = WFh + (size_t)layer * 1048576;
        const unsigned short* WFl_l = WFl + (size_t)layer * 1048576;
        unsigned short* Xi = (layer & 1) ? XFB : XFA;
        unsigned short* Xo = (layer & 1) ? XFA : XFB;

        k_fused<<<256, 512, 0, stream>>>(UFh_l, UFl_l, WFh_l, WFl_l,
                                         Xi, Xi + XFPLANE, Xo, Xo + XFPLANE,
                                         preF, mask, bias, xRaw, bar,
                                         flip, writeX,
                                         (unsigned)(layer * 256),
                                         (unsigned)(16 * (layer + 1)));
    }

    k_out<<<TQ, 256, 0, stream>>>(xRaw, Wo, bo, out);
}